// Round 2
// baseline (175.356 us; speedup 1.0000x reference)
//
#include <hip/hip_runtime.h>

// Round 6 (resubmit — round 6 bench hit GPUAcquisitionTimeout, no data):
// 2D edge bucketing (8 src-ranges x 8 dst-ranges = 64 buckets),
// XCD-pinned processing (bucket = bs*8 + blockIdx%8) so each XCD's 4MB L2
// holds its fg slice (800KB, pinned all kernel) + one rotating fd slice.
// Theory: the ~61 G lines/s gather wall is the L2-miss path (~3.3 TB/s via
// L3); 66% hit -> ~100% hit should drop edge gathers toward the L2-hit bound.
// Binning is a single-pass LDS-histogram counting scatter (64 global atomics
// per block, dense 8B-record streams -> L2 write-merge), NOT the full sort
// that cost 170us in round 4/5.

#define FD 64
#define NBUCK 64
#define BIN_CHUNK 2048

__device__ __forceinline__ int q8pack(float v0, float v1, float v2, float v3, float inv) {
    float a0 = fminf(fmaxf(v0 * inv, -127.f), 127.f);
    float a1 = fminf(fmaxf(v1 * inv, -127.f), 127.f);
    float a2 = fminf(fmaxf(v2 * inv, -127.f), 127.f);
    float a3 = fminf(fmaxf(v3 * inv, -127.f), 127.f);
    int q0 = ((int)rintf(a0)) & 0xff;
    int q1 = ((int)rintf(a1)) & 0xff;
    int q2 = ((int)rintf(a2)) & 0xff;
    int q3 = ((int)rintf(a3)) & 0xff;
    return q0 | (q1 << 8) | (q2 << 16) | (q3 << 24);
}

__global__ void pack_kernel(const float4* __restrict__ xd, const float4* __restrict__ hd,
                            const float4* __restrict__ xg, const float4* __restrict__ hg,
                            int2* __restrict__ fd, int2* __restrict__ fg,
                            float* __restrict__ sd, float* __restrict__ sg,
                            unsigned* __restrict__ cursor,
                            int n_d, int n_g)
{
    // fold bucket-cursor init into the first kernel of the launch
    if (cursor != nullptr && blockIdx.x == 0 && threadIdx.x < NBUCK)
        cursor[threadIdx.x] = 0u;

    int tid  = (int)(blockIdx.x * blockDim.x + threadIdx.x);
    int node = tid >> 4;
    int lane = threadIdx.x & 15;
    int total = n_d + n_g;
    if (node >= total) return;

    const float4* x; const float4* h; int2* o; float* s; int n;
    if (node < n_d) { x = xd; h = hd; o = fd; s = sd; n = node; }
    else            { x = xg; h = hg; o = fg; s = sg; n = node - n_d; }

    float4 a = x[(size_t)n * 16 + lane];
    float4 b = h[(size_t)n * 16 + lane];

    float ss = a.x*a.x + a.y*a.y + a.z*a.z + a.w*a.w
             + b.x*b.x + b.y*b.y + b.z*b.z + b.w*b.w;
    #pragma unroll
    for (int m = 8; m >= 1; m >>= 1) ss += __shfl_xor(ss, m);
    float r = rsqrtf(ss);

    a.x *= r; a.y *= r; a.z *= r; a.w *= r;
    b.x *= r; b.y *= r; b.z *= r; b.w *= r;

    float mx = fmaxf(fmaxf(fmaxf(fabsf(a.x), fabsf(a.y)), fmaxf(fabsf(a.z), fabsf(a.w))),
                     fmaxf(fmaxf(fabsf(b.x), fabsf(b.y)), fmaxf(fabsf(b.z), fabsf(b.w))));
    #pragma unroll
    for (int m = 8; m >= 1; m >>= 1) mx = fmaxf(mx, __shfl_xor(mx, m));

    float inv = 127.0f / mx;

    int2 w;
    w.x = q8pack(a.x, a.y, a.z, a.w, inv);
    w.y = q8pack(b.x, b.y, b.z, b.w, inv);
    o[(size_t)n * 16 + lane] = w;

    if (lane == 0) s[n] = mx * (1.0f / 127.0f);
}

// Counting scatter into 64 (src-range x dst-range) buckets.
// Per-block LDS histogram -> one global atomicAdd per touched bucket per
// block -> positioned writes. Records: {src | dst<<16, eid} (8 B).
__global__ __launch_bounds__(256, 4)
void bin_kernel(const int* __restrict__ src, const int* __restrict__ dst,
                uint2* __restrict__ bins, unsigned* __restrict__ cursor,
                int n_edges, int cap, unsigned mul_s, unsigned mul_d)
{
    __shared__ unsigned hist[NBUCK];
    __shared__ unsigned base[NBUCK];
    int t = threadIdx.x;
    if (t < NBUCK) hist[t] = 0u;
    __syncthreads();

    int start = (int)blockIdx.x * BIN_CHUNK;
    unsigned pk[8]; unsigned bk[8];
    #pragma unroll
    for (int k = 0; k < 8; ++k) {
        int e = start + t + k * 256;
        unsigned b = 0xffffffffu, p = 0u;
        if (e < n_edges) {
            unsigned s = (unsigned)src[e];
            unsigned d = (unsigned)dst[e];
            unsigned bs = min(7u, (s * mul_s) >> 20);
            unsigned bd = min(7u, (d * mul_d) >> 20);
            b = bs * 8u + bd;
            p = s | (d << 16);
            atomicAdd(&hist[b], 1u);
        }
        pk[k] = p; bk[k] = b;
    }
    __syncthreads();
    if (t < NBUCK) {
        unsigned h = hist[t];
        base[t] = h ? atomicAdd(&cursor[t], h) : 0u;
        hist[t] = 0u;                      // reuse as running intra-block offset
    }
    __syncthreads();
    #pragma unroll
    for (int k = 0; k < 8; ++k) {
        unsigned b = bk[k];
        if (b != 0xffffffffu) {
            unsigned r = atomicAdd(&hist[b], 1u);
            unsigned pos = base[b] + r;
            if (pos < (unsigned)cap)
                bins[(size_t)b * cap + pos] =
                    make_uint2(pk[k], (unsigned)(start + t + k * 256));
        }
    }
}

__device__ __forceinline__ int dot4(int a, int b, int c) {
    return __builtin_amdgcn_sdot4(a, b, c, false);   // v_dot4_i32_i8
}

// Bucketed edge kernel: block i -> xcd = i&7, j = i>>3; bucket = (j/bpb)*8 + xcd.
// Each XCD walks fd slices 0..7 while its fg slice stays L2-resident.
__global__ __launch_bounds__(256, 8)
void edge_kernel_bkt(const int4* __restrict__ fd, const int4* __restrict__ fg,
                     const float* __restrict__ sd, const float* __restrict__ sg,
                     const uint2* __restrict__ bins, const unsigned* __restrict__ cursor,
                     float* __restrict__ out, int cap, int bpb)
{
    int i     = (int)blockIdx.x;
    int xcd   = i & 7;
    int j     = i >> 3;
    int bs    = j / bpb;
    int chunk = j - bs * bpb;
    int b     = bs * 8 + xcd;

    int count = (int)cursor[b];
    int grp  = threadIdx.x >> 3;
    int lane = threadIdx.x & 7;
    int e0   = chunk * 64 + grp * 2;
    if (e0 >= count) return;
    bool has1 = (e0 + 1) < count;

    const uint2* bb = bins + (size_t)b * cap;
    // 16B-aligned paired record load (e0 even, cap multiple of 64).
    uint4 rr = ((const uint4*)bb)[e0 >> 1];
    int s0 = (int)(rr.x & 0xffffu), d0 = (int)(rr.x >> 16);
    int s1 = (int)(rr.z & 0xffffu), d1 = (int)(rr.z >> 16);
    // when !has1, s1/d1 are garbage but stay inside d_ws; output is guarded.

    int4 a0 = fd[(size_t)s0 * 8 + lane];
    int4 b0 = fg[(size_t)d0 * 8 + lane];
    int4 a1 = fd[(size_t)s1 * 8 + lane];
    int4 b1 = fg[(size_t)d1 * 8 + lane];

    int acc0 = dot4(a0.x, b0.x, dot4(a0.y, b0.y, dot4(a0.z, b0.z, dot4(a0.w, b0.w, 0))));
    int acc1 = dot4(a1.x, b1.x, dot4(a1.y, b1.y, dot4(a1.z, b1.z, dot4(a1.w, b1.w, 0))));

    acc0 += __shfl_xor(acc0, 4);
    acc0 += __shfl_xor(acc0, 2);
    acc0 += __shfl_xor(acc0, 1);
    acc1 += __shfl_xor(acc1, 4);
    acc1 += __shfl_xor(acc1, 2);
    acc1 += __shfl_xor(acc1, 1);

    if (lane == 0) {
        out[rr.y] = (float)acc0 * sd[s0] * sg[d0];
        if (has1) out[rr.w] = (float)acc1 * sd[s1] * sg[d1];
    }
}

// Fallback (round-5 proven path) if ws can't hold bins or ids exceed 16 bit.
__global__ __launch_bounds__(256, 8)
void edge_kernel2(const int4* __restrict__ fd, const int4* __restrict__ fg,
                  const float* __restrict__ sd, const float* __restrict__ sg,
                  const int* __restrict__ src, const int* __restrict__ dst,
                  float* __restrict__ out, int n_edges)
{
    int tid  = (int)(blockIdx.x * blockDim.x + threadIdx.x);
    int lane = threadIdx.x & 7;
    int g    = tid >> 3;
    int e0   = g * 2;
    if (e0 >= n_edges) return;
    int  e1   = min(e0 + 1, n_edges - 1);
    bool has1 = (e0 + 1) < n_edges;

    int s0 = src[e0], d0 = dst[e0];
    int s1 = src[e1], d1 = dst[e1];

    int4 a0 = fd[(size_t)s0 * 8 + lane];
    int4 b0 = fg[(size_t)d0 * 8 + lane];
    int4 a1 = fd[(size_t)s1 * 8 + lane];
    int4 b1 = fg[(size_t)d1 * 8 + lane];

    int acc0 = dot4(a0.x, b0.x, dot4(a0.y, b0.y, dot4(a0.z, b0.z, dot4(a0.w, b0.w, 0))));
    int acc1 = dot4(a1.x, b1.x, dot4(a1.y, b1.y, dot4(a1.z, b1.z, dot4(a1.w, b1.w, 0))));

    acc0 += __shfl_xor(acc0, 4);
    acc0 += __shfl_xor(acc0, 2);
    acc0 += __shfl_xor(acc0, 1);
    acc1 += __shfl_xor(acc1, 4);
    acc1 += __shfl_xor(acc1, 2);
    acc1 += __shfl_xor(acc1, 1);

    if (lane == 0) {
        out[e0] = (float)acc0 * sd[s0] * sg[d0];
        if (has1) out[e1] = (float)acc1 * sd[s1] * sg[d1];
    }
}

extern "C" void kernel_launch(void* const* d_in, const int* in_sizes, int n_in,
                              void* d_out, int out_size, void* d_ws, size_t ws_size,
                              hipStream_t stream) {
    const float* xd = (const float*)d_in[0];
    const float* hd = (const float*)d_in[1];
    const float* xg = (const float*)d_in[2];
    const float* hg = (const float*)d_in[3];
    const int*  src = (const int*)d_in[4];
    const int*  dst = (const int*)d_in[5];

    int n_d     = in_sizes[0] / FD;
    int n_g     = in_sizes[2] / FD;
    int n_edges = in_sizes[4];

    // bucket capacity: mean + ~25% slack, multiple of 64
    int cap = n_edges / 64 + n_edges / 256 + 4096;
    cap = (cap + 63) & ~63;

    size_t fd_b   = (size_t)n_d * 128;
    size_t fg_b   = (size_t)n_g * 128;
    size_t bins_b = (size_t)NBUCK * (size_t)cap * sizeof(uint2);
    size_t need   = fd_b + fg_b + bins_b
                  + (size_t)(n_d + n_g) * sizeof(float) + NBUCK * sizeof(unsigned) + 256;

    bool bucketed = (need <= ws_size) && (n_d < 65536) && (n_g < 65536) && (n_edges > 0);

    // ws layout: fd | fg | [bins] | sd | sg | [cursor]
    char* ws = (char*)d_ws;
    int2*  fd = (int2*)ws;  ws += fd_b;
    int2*  fg = (int2*)ws;  ws += fg_b;
    uint2* bins = nullptr;
    if (bucketed) { bins = (uint2*)ws; ws += bins_b; }
    float* sd = (float*)ws; ws += (size_t)n_d * sizeof(float);
    float* sg = (float*)ws; ws += (size_t)n_g * sizeof(float);
    unsigned* cursor = nullptr;
    if (bucketed) { cursor = (unsigned*)ws; }
    float* out = (float*)d_out;

    int total_nodes = n_d + n_g;
    int nb1 = (total_nodes * 16 + 255) / 256;
    pack_kernel<<<nb1, 256, 0, stream>>>((const float4*)xd, (const float4*)hd,
                                         (const float4*)xg, (const float4*)hg,
                                         fd, fg, sd, sg, cursor, n_d, n_g);

    if (bucketed) {
        unsigned mul_s = (8u << 20) / (unsigned)n_d;
        unsigned mul_d = (8u << 20) / (unsigned)n_g;
        int nbin = (n_edges + BIN_CHUNK - 1) / BIN_CHUNK;
        bin_kernel<<<nbin, 256, 0, stream>>>(src, dst, bins, cursor,
                                             n_edges, cap, mul_s, mul_d);

        int bpb = cap / 64;             // blocks per bucket (64 edges/block)
        int nb2 = NBUCK * bpb;
        edge_kernel_bkt<<<nb2, 256, 0, stream>>>((const int4*)fd, (const int4*)fg,
                                                 sd, sg, bins, cursor, out, cap, bpb);
    } else {
        long long groups = ((long long)n_edges + 1) / 2;
        int nb2 = (int)((groups * 8 + 255) / 256);
        edge_kernel2<<<nb2, 256, 0, stream>>>((const int4*)fd, (const int4*)fg,
                                              sd, sg, src, dst, out, n_edges);
    }
}